// Round 5
// baseline (254.969 us; speedup 1.0000x reference)
//
#include <hip/hip_runtime.h>

// B=8, S=256, C=256, V=64 — fp32 inputs/outputs, fp16 MFMA internally.
// out[b,s,z,k] = tanh( BIL + r[b,z,k] + t[b,s,k] )
//   W_eff[i,j,k] = W[i,j,k] + (i==j)*linmul_w[k,j]
//   tmp[(b,s)][k][j] = sum_i ctx[b,s,i] * W_eff[i,j,k]          (GEMM1, n'=k*256+j)
//   BIL[b,s,z,k]     = sum_j ctx[b,z,j] * tmp[(b,s)][k][j]      (GEMM2)
//   r[b,z,k] = ctx[b,z,:]·(lin1_w[k,:]+lindiff_w[k,:]) + lin1_b[k]
//   t[b,s,k] = ctx[b,s,:]·(lin2_w[k,:]-lindiff_w[k,:]) + lin2_b[k]
//              + bias[k] + linmul_b[k] + lindiff_b[k]
//
// R5: fixes R4's cross-wave race. vmcnt is PER-WAVE, so the counted wait must
// come BEFORE a barrier: stage(next) -> vmcnt(4) -> s_barrier (=> all waves'
// current-tile loads landed) -> ds_read+MFMA -> s_barrier (=> buffer reusable).
// Never vmcnt(0) in the main loop. Barriers are asm with "memory" clobber
// (raw builtin isn't a compiler fence). T5 setprio around MFMA cluster.
// Math order unchanged vs R2/R3.

typedef __attribute__((ext_vector_type(8))) _Float16 half8;
typedef __attribute__((ext_vector_type(4))) _Float16 half4v;
typedef __attribute__((ext_vector_type(4))) float f32x4;

__device__ __forceinline__ void async16(const void* g, void* l) {
  __builtin_amdgcn_global_load_lds(
      (__attribute__((address_space(1))) void*)g,
      (__attribute__((address_space(3))) void*)l, 16, 0, 0);
}

// ---- prep 1: wt[n'=(k*256+j)][i] = fp16( W[i][j][k] + (i==j)*lmw[k*256+j] ) ----
__global__ __launch_bounds__(256) void prep_wt(const float* __restrict__ W,
                                               const float* __restrict__ lmw,
                                               _Float16* __restrict__ wt) {
  __shared__ _Float16 T[256 * 68];  // [i][k], pad 64->68
  const int t = threadIdx.x;
  const int j = blockIdx.x;
#pragma unroll
  for (int p = 0; p < 16; ++p) {
    int i = p * 16 + (t >> 4);
    int c = t & 15;  // float4 chunk along k
    float4 v = *(const float4*)&W[(size_t)i * 16384 + j * 64 + c * 4];
    if (i == j) {
      v.x += lmw[(c * 4 + 0) * 256 + j];
      v.y += lmw[(c * 4 + 1) * 256 + j];
      v.z += lmw[(c * 4 + 2) * 256 + j];
      v.w += lmw[(c * 4 + 3) * 256 + j];
    }
    half4v o;
    o[0] = (_Float16)v.x; o[1] = (_Float16)v.y;
    o[2] = (_Float16)v.z; o[3] = (_Float16)v.w;
    *(half4v*)&T[i * 68 + c * 4] = o;
  }
  __syncthreads();
  const int k = t >> 2, i0 = (t & 3) * 64;
  _Float16* dst = wt + ((size_t)(k * 256 + j)) * 256 + i0;
#pragma unroll
  for (int u = 0; u < 64; u += 8) {
    half8 o;
#pragma unroll
    for (int e = 0; e < 8; ++e) o[e] = T[(i0 + u + e) * 68 + k];
    *(half8*)(dst + u) = o;
  }
}

// ---- prep 2 (merged): ch = fp16(ctx); r[row][k], t[row][k]; 16 rows/block ----
__global__ __launch_bounds__(256) void prep_rt(
    const float* __restrict__ ctx, const float* __restrict__ bias,
    const float* __restrict__ l1w, const float* __restrict__ l1b,
    const float* __restrict__ l2w, const float* __restrict__ l2b,
    const float* __restrict__ lmb, const float* __restrict__ ldw,
    const float* __restrict__ ldb, float* __restrict__ rbuf,
    float* __restrict__ tbuf, _Float16* __restrict__ ch) {
  __shared__ float Cs[16 * 256];
  const int t = threadIdx.x;
  const int row0 = blockIdx.x * 16;
#pragma unroll
  for (int p = 0; p < 4; ++p)
    ((float4*)Cs)[p * 256 + t] =
        ((const float4*)(ctx + (size_t)row0 * 256))[p * 256 + t];
  __syncthreads();
  // fp16 conversion of these 16 rows (was prep_ctx)
  {
    half8 h0, h1;
#pragma unroll
    for (int e = 0; e < 8; ++e) {
      h0[e] = (_Float16)Cs[t * 16 + e];
      h1[e] = (_Float16)Cs[t * 16 + 8 + e];
    }
    *(half8*)&ch[(size_t)row0 * 256 + t * 16] = h0;
    *(half8*)&ch[(size_t)row0 * 256 + t * 16 + 8] = h1;
  }
  const int k = t & 63, lr = t >> 6;  // wave lr handles rows lr*4 .. lr*4+3
  const float* l1r = l1w + k * 256;
  const float* l2r = l2w + k * 256;
  const float* ldr = ldw + k * 256;
  float a1[4] = {0.f, 0.f, 0.f, 0.f};
  float a2[4] = {0.f, 0.f, 0.f, 0.f};
  for (int c = 0; c < 256; c += 4) {
    float4 w1 = *(const float4*)(l1r + c);
    float4 w2 = *(const float4*)(l2r + c);
    float4 wd = *(const float4*)(ldr + c);
    float4 s1, s2;
    s1.x = w1.x + wd.x; s1.y = w1.y + wd.y; s1.z = w1.z + wd.z; s1.w = w1.w + wd.w;
    s2.x = w2.x - wd.x; s2.y = w2.y - wd.y; s2.z = w2.z - wd.z; s2.w = w2.w - wd.w;
#pragma unroll
    for (int u = 0; u < 4; ++u) {
      float4 cv = *(const float4*)(&Cs[(lr * 4 + u) * 256 + c]);
      a1[u] += cv.x * s1.x + cv.y * s1.y + cv.z * s1.z + cv.w * s1.w;
      a2[u] += cv.x * s2.x + cv.y * s2.y + cv.z * s2.z + cv.w * s2.w;
    }
  }
  float tb = l2b[k] + bias[k] + lmb[k] + ldb[k];
  float rb = l1b[k];
#pragma unroll
  for (int u = 0; u < 4; ++u) {
    int row = row0 + lr * 4 + u;
    rbuf[row * 64 + k] = a1[u] + rb;
    tbuf[row * 64 + k] = a2[u] + tb;
  }
}

// ---- GEMM1: tmp[m][n'] = ctx_h[m][:] . wt[n'][:]  (M=2048, N=16384, K=256) ----
// BK=32 double-buffered, counted vmcnt BEFORE barrier (cross-wave safe),
// two asm barriers per K-step, setprio around MFMA. Swapped MFMA
// (acc[ni][mi]) -> per-wave LDS-transpose epilogue -> half8 coalesced stores.
__global__ __launch_bounds__(256) void gemm1(const _Float16* __restrict__ ch,
                                             const _Float16* __restrict__ wt,
                                             _Float16* __restrict__ tmp) {
  // 36 KB pool. K-loop: buf0 = [0,8192) halfs (As@0, Bs@4096),
  //                     buf1 = [8192,16384). Epilogue Sw tiles alias the pool.
  __shared__ _Float16 pool[4 * 64 * 72];
  const int t = threadIdx.x;
  const int lane = t & 63, wave = t >> 6;
  const int d = blockIdx.x + blockIdx.y * 128;
  const int w = (d & 7) * 256 + (d >> 3);
  const int m0 = (w & 15) * 128, n0 = (w >> 4) * 128;
  const int wm = (wave & 1) * 64, wn = (wave >> 1) * 64;
  const int r = lane & 15, q = lane >> 4;
  f32x4 acc[4][4] = {};  // acc[ni][mi]
  // Staging: row = (t>>2) (+64 for 2nd half), LDS chunk c = t&3 holds global
  // chunk c ^ ((row>>1)&3) = c ^ ((t>>3)&3). LDS dest linear: t*8.
  const int cg = (t & 3) ^ ((t >> 3) & 3);
  const _Float16* gA = ch + (size_t)(m0 + (t >> 2)) * 256 + cg * 8;
  const _Float16* gB = wt + (size_t)(n0 + (t >> 2)) * 256 + cg * 8;
#define G1_STAGE(buf, k0)                                      \
  {                                                            \
    _Float16* Ab = pool + (buf)*8192;                          \
    _Float16* Bb = pool + (buf)*8192 + 4096;                   \
    async16(gA + (k0), &Ab[t * 8]);                            \
    async16(gA + 64 * 256 + (k0), &Ab[2048 + t * 8]);          \
    async16(gB + (k0), &Bb[t * 8]);                            \
    async16(gB + 64 * 256 + (k0), &Bb[2048 + t * 8]);          \
  }
  G1_STAGE(0, 0);
  const int ca = (q ^ ((r >> 1) & 3)) * 8;  // swizzled 16B chunk (2-way max)
#pragma unroll
  for (int ks = 0; ks < 8; ++ks) {
    if (ks < 7) {
      G1_STAGE((ks + 1) & 1, (ks + 1) * 32);
      asm volatile("s_waitcnt vmcnt(4)" ::: "memory");  // own tile-ks loads done
    } else {
      asm volatile("s_waitcnt vmcnt(0)" ::: "memory");
    }
    asm volatile("s_barrier" ::: "memory");  // => ALL waves' tile-ks loads done
    const _Float16* Ab = pool + (ks & 1) * 8192;
    const _Float16* Bb = Ab + 4096;
    half8 a[4], b[4];
#pragma unroll
    for (int mi = 0; mi < 4; ++mi)
      a[mi] = *(const half8*)&Ab[(wm + mi * 16 + r) * 32 + ca];
#pragma unroll
    for (int ni = 0; ni < 4; ++ni)
      b[ni] = *(const half8*)&Bb[(wn + ni * 16 + r) * 32 + ca];
    __builtin_amdgcn_s_setprio(1);
#pragma unroll
    for (int ni = 0; ni < 4; ++ni)
#pragma unroll
      for (int mi = 0; mi < 4; ++mi)
        acc[ni][mi] = __builtin_amdgcn_mfma_f32_16x16x32_f16(
            b[ni], a[mi], acc[ni][mi], 0, 0, 0);
    __builtin_amdgcn_s_setprio(0);
    asm volatile("s_barrier" ::: "memory");  // all reads done; buf reusable
  }
#undef G1_STAGE
  // Epilogue: per-wave private 64x72 LDS tile [m][n] (disjoint per wave, no
  // barrier needed after the final loop barrier), then half8 coalesced stores.
  _Float16* Sw = pool + wave * 4608;
#pragma unroll
  for (int ni = 0; ni < 4; ++ni)
#pragma unroll
    for (int mi = 0; mi < 4; ++mi) {
      half4v h;
#pragma unroll
      for (int e = 0; e < 4; ++e) h[e] = (_Float16)acc[ni][mi][e];
      *(half4v*)&Sw[(mi * 16 + r) * 72 + ni * 16 + q * 4] = h;
    }
  const int g2 = lane >> 3, c2 = lane & 7;
  _Float16* dst = tmp + (size_t)(m0 + wm) * 16384 + (n0 + wn);
#pragma unroll
  for (int u = 0; u < 8; ++u) {
    int row = u * 8 + g2;
    half8 vv = *(const half8*)&Sw[row * 72 + c2 * 8];
    *(half8*)(dst + (size_t)row * 16384 + c2 * 8) = vv;
  }
}

// ---- GEMM2 + epilogue: one wide GEMM per batch b ----
// out_b[z][(s,k)] = ctx_b[z][:] . tmp_b[(s*64+k)][:]  (M=256, N=16384, K=256)
// Same corrected BK=32 counted-vmcnt pipeline. acc[ni][mi]: lane holds 4
// consecutive k -> float4 r/t loads + tanh + float4 out stores.
__global__ __launch_bounds__(256) void gemm2(const _Float16* __restrict__ ch,
                                             const _Float16* __restrict__ tmp,
                                             const float* __restrict__ rbuf,
                                             const float* __restrict__ tbuf,
                                             float* __restrict__ out) {
  __shared__ _Float16 pool[16384];  // 32 KB: buf0 @0 (As@0,Bs@4096), buf1 @8192
  const int t = threadIdx.x;
  const int lane = t & 63, wave = t >> 6;
  const int d = blockIdx.x;
  const int b = d & 7;               // xcd = b
  const int idx = d >> 3;            // [0,256)
  const int m0 = (idx & 1) * 128;    // z-tile
  const int n0 = (idx >> 1) * 128;   // (s,k)-tile
  const int wm = (wave & 1) * 64, wn = (wave >> 1) * 64;
  const int r = lane & 15, q = lane >> 4;
  f32x4 acc[4][4] = {};  // acc[ni][mi]
  const _Float16* chb = ch + (size_t)b * 65536;
  const _Float16* tmb = tmp + (size_t)b * 4194304;
  const int cg = (t & 3) ^ ((t >> 3) & 3);
  const _Float16* gA = chb + (size_t)(m0 + (t >> 2)) * 256 + cg * 8;
  const _Float16* gB = tmb + (size_t)(n0 + (t >> 2)) * 256 + cg * 8;
#define G2_STAGE(buf, k0)                                      \
  {                                                            \
    _Float16* Ab = pool + (buf)*8192;                          \
    _Float16* Bb = pool + (buf)*8192 + 4096;                   \
    async16(gA + (k0), &Ab[t * 8]);                            \
    async16(gA + 64 * 256 + (k0), &Ab[2048 + t * 8]);          \
    async16(gB + (k0), &Bb[t * 8]);                            \
    async16(gB + 64 * 256 + (k0), &Bb[2048 + t * 8]);          \
  }
  G2_STAGE(0, 0);
  const int ca = (q ^ ((r >> 1) & 3)) * 8;
#pragma unroll
  for (int ks = 0; ks < 8; ++ks) {
    if (ks < 7) {
      G2_STAGE((ks + 1) & 1, (ks + 1) * 32);
      asm volatile("s_waitcnt vmcnt(4)" ::: "memory");
    } else {
      asm volatile("s_waitcnt vmcnt(0)" ::: "memory");
    }
    asm volatile("s_barrier" ::: "memory");
    const _Float16* Ab = pool + (ks & 1) * 8192;
    const _Float16* Bb = Ab + 4096;
    half8 a[4], bf[4];
#pragma unroll
    for (int mi = 0; mi < 4; ++mi)
      a[mi] = *(const half8*)&Ab[(wm + mi * 16 + r) * 32 + ca];
#pragma unroll
    for (int ni = 0; ni < 4; ++ni)
      bf[ni] = *(const half8*)&Bb[(wn + ni * 16 + r) * 32 + ca];
    __builtin_amdgcn_s_setprio(1);
#pragma unroll
    for (int ni = 0; ni < 4; ++ni)
#pragma unroll
      for (int mi = 0; mi < 4; ++mi)
        acc[ni][mi] = __builtin_amdgcn_mfma_f32_16x16x32_f16(
            bf[ni], a[mi], acc[ni][mi], 0, 0, 0);
    __builtin_amdgcn_s_setprio(0);
    asm volatile("s_barrier" ::: "memory");
  }
#undef G2_STAGE
  // Epilogue: n = s_local*64 + k; per lane 4 consecutive k (never cross s).
  const int s = (n0 >> 6) + (wn >> 6);          // global s for this wave
  const float* rb = rbuf + (size_t)b * 16384;
  const float* tb = tbuf + ((size_t)(b * 256 + s)) * 64;
  float* ob = out + (size_t)b * 4194304 + (size_t)s * 16384;
#pragma unroll
  for (int ni = 0; ni < 4; ++ni)
#pragma unroll
    for (int mi = 0; mi < 4; ++mi) {
      int z = m0 + wm + mi * 16 + r;
      int k0 = ni * 16 + q * 4;
      f32x4 rv = *(const f32x4*)&rb[z * 64 + k0];
      f32x4 tv = *(const f32x4*)&tb[k0];
      f32x4 o;
#pragma unroll
      for (int e = 0; e < 4; ++e) {
        float x = acc[ni][mi][e] + rv[e] + tv[e];
        float ax = fabsf(x);
        float ev = __expf(-2.0f * ax);
        float y = (1.0f - ev) / (1.0f + ev);
        o[e] = copysignf(y, x);
      }
      *(f32x4*)&ob[z * 64 + k0] = o;
    }
}

extern "C" void kernel_launch(void* const* d_in, const int* in_sizes, int n_in,
                              void* d_out, int out_size, void* d_ws, size_t ws_size,
                              hipStream_t stream) {
  const float* ctx  = (const float*)d_in[0];
  const float* W    = (const float*)d_in[1];
  const float* bias = (const float*)d_in[2];
  const float* l1w  = (const float*)d_in[3];
  const float* l1b  = (const float*)d_in[4];
  const float* l2w  = (const float*)d_in[5];
  const float* l2b  = (const float*)d_in[6];
  const float* lmw  = (const float*)d_in[7];
  const float* lmb  = (const float*)d_in[8];
  const float* ldw  = (const float*)d_in[9];
  const float* ldb  = (const float*)d_in[10];
  float* out = (float*)d_out;

  char* ws = (char*)d_ws;
  _Float16* ch  = (_Float16*)ws;                               // 1 MiB ctx fp16
  _Float16* wt  = (_Float16*)(ws + (1u << 20));                // 8 MiB W_eff^T fp16
  _Float16* tmp = (_Float16*)(ws + (9u << 20));                // 64 MiB tmp fp16
  float* rbuf = (float*)(ws + (73u << 20));                    // 512 KiB
  float* tbuf = rbuf + 2048 * 64;                              // 512 KiB

  prep_rt<<<128, 256, 0, stream>>>(ctx, bias, l1w, l1b, l2w, l2b, lmb, ldw, ldb,
                                   rbuf, tbuf, ch);
  prep_wt<<<256, 256, 0, stream>>>(W, lmw, wt);
  gemm1<<<dim3(128, 16), 256, 0, stream>>>(ch, wt, tmp);
  gemm2<<<2048, 256, 0, stream>>>(ch, tmp, rbuf, tbuf, out);
}

// Round 6
// 243.152 us; speedup vs baseline: 1.0486x; 1.0486x over previous
//
#include <hip/hip_runtime.h>

// B=8, S=256, C=256, V=64 — fp32 inputs/outputs, fp16 MFMA internally.
// out[b,s,z,k] = tanh( BIL + r[b,z,k] + t[b,s,k] )
//   W_eff[i,j,k] = W[i,j,k] + (i==j)*linmul_w[k,j]
//   tmp[(b,s)][k][j] = sum_i ctx[b,s,i] * W_eff[i,j,k]          (GEMM1, n'=k*256+j)
//   BIL[b,s,z,k]     = sum_j ctx[b,z,j] * tmp[(b,s)][k][j]      (GEMM2)
//   r[b,z,k] = ctx[b,z,:]·(lin1_w[k,:]+lindiff_w[k,:]) + lin1_b[k]
//   t[b,s,k] = ctx[b,s,:]·(lin2_w[k,:]-lindiff_w[k,:]) + lin2_b[k]
//              + bias[k] + linmul_b[k] + lindiff_b[k]
//
// R6: best-of ledger. GEMM K-loops back to the R2/R3 proven form (BK=64,
// two __syncthreads per step — measured faster than counted-vmcnt dbuf R5
// and than BK=32 R0/R1). All preps merged into ONE kernel (384 blocks:
// [0,128) = ctx->fp16 + r/t rows; [128,384) = W_eff^T build), saving a
// launch and overlapping their memory phases. T2 LDS swizzle + XCD-chunked
// block swizzles kept. Math order unchanged (absmax must stay 0.01953125).

typedef __attribute__((ext_vector_type(8))) _Float16 half8;
typedef __attribute__((ext_vector_type(4))) _Float16 half4v;
typedef __attribute__((ext_vector_type(4))) float f32x4;

__device__ __forceinline__ void async16(const void* g, void* l) {
  __builtin_amdgcn_global_load_lds(
      (__attribute__((address_space(1))) void*)g,
      (__attribute__((address_space(3))) void*)l, 16, 0, 0);
}

// ---- prep (merged): blocks [0,128): ch + r/t; blocks [128,384): wt ----
__global__ __launch_bounds__(256) void prep_all(
    const float* __restrict__ ctx, const float* __restrict__ W,
    const float* __restrict__ bias,
    const float* __restrict__ l1w, const float* __restrict__ l1b,
    const float* __restrict__ l2w, const float* __restrict__ l2b,
    const float* __restrict__ lmw, const float* __restrict__ lmb,
    const float* __restrict__ ldw, const float* __restrict__ ldb,
    float* __restrict__ rbuf, float* __restrict__ tbuf,
    _Float16* __restrict__ ch, _Float16* __restrict__ wt) {
  __shared__ __align__(16) char smem[256 * 68 * 2];  // 34 KB, union of uses
  const int t = threadIdx.x;
  if (blockIdx.x >= 128) {
    // ---- wt[n'=(k*256+j)][i] = fp16( W[i][j][k] + (i==j)*lmw[k*256+j] ) ----
    _Float16* T = (_Float16*)smem;  // [i][k], pad 64->68
    const int j = blockIdx.x - 128;
#pragma unroll
    for (int p = 0; p < 16; ++p) {
      int i = p * 16 + (t >> 4);
      int c = t & 15;  // float4 chunk along k
      float4 v = *(const float4*)&W[(size_t)i * 16384 + j * 64 + c * 4];
      if (i == j) {
        v.x += lmw[(c * 4 + 0) * 256 + j];
        v.y += lmw[(c * 4 + 1) * 256 + j];
        v.z += lmw[(c * 4 + 2) * 256 + j];
        v.w += lmw[(c * 4 + 3) * 256 + j];
      }
      half4v o;
      o[0] = (_Float16)v.x; o[1] = (_Float16)v.y;
      o[2] = (_Float16)v.z; o[3] = (_Float16)v.w;
      *(half4v*)&T[i * 68 + c * 4] = o;
    }
    __syncthreads();
    const int k = t >> 2, i0 = (t & 3) * 64;
    _Float16* dst = wt + ((size_t)(k * 256 + j)) * 256 + i0;
#pragma unroll
    for (int u = 0; u < 64; u += 8) {
      half8 o;
#pragma unroll
      for (int e = 0; e < 8; ++e) o[e] = T[(i0 + u + e) * 68 + k];
      *(half8*)(dst + u) = o;
    }
    return;
  }
  // ---- ch = fp16(ctx); r[row][k], t[row][k]; 16 rows/block ----
  float* Cs = (float*)smem;  // 16*256 floats
  const int row0 = blockIdx.x * 16;
#pragma unroll
  for (int p = 0; p < 4; ++p)
    ((float4*)Cs)[p * 256 + t] =
        ((const float4*)(ctx + (size_t)row0 * 256))[p * 256 + t];
  __syncthreads();
  {
    half8 h0, h1;
#pragma unroll
    for (int e = 0; e < 8; ++e) {
      h0[e] = (_Float16)Cs[t * 16 + e];
      h1[e] = (_Float16)Cs[t * 16 + 8 + e];
    }
    *(half8*)&ch[(size_t)row0 * 256 + t * 16] = h0;
    *(half8*)&ch[(size_t)row0 * 256 + t * 16 + 8] = h1;
  }
  const int k = t & 63, lr = t >> 6;  // wave lr handles rows lr*4 .. lr*4+3
  const float* l1r = l1w + k * 256;
  const float* l2r = l2w + k * 256;
  const float* ldr = ldw + k * 256;
  float a1[4] = {0.f, 0.f, 0.f, 0.f};
  float a2[4] = {0.f, 0.f, 0.f, 0.f};
  for (int c = 0; c < 256; c += 4) {
    float4 w1 = *(const float4*)(l1r + c);
    float4 w2 = *(const float4*)(l2r + c);
    float4 wd = *(const float4*)(ldr + c);
    float4 s1, s2;
    s1.x = w1.x + wd.x; s1.y = w1.y + wd.y; s1.z = w1.z + wd.z; s1.w = w1.w + wd.w;
    s2.x = w2.x - wd.x; s2.y = w2.y - wd.y; s2.z = w2.z - wd.z; s2.w = w2.w - wd.w;
#pragma unroll
    for (int u = 0; u < 4; ++u) {
      float4 cv = *(const float4*)(&Cs[(lr * 4 + u) * 256 + c]);
      a1[u] += cv.x * s1.x + cv.y * s1.y + cv.z * s1.z + cv.w * s1.w;
      a2[u] += cv.x * s2.x + cv.y * s2.y + cv.z * s2.z + cv.w * s2.w;
    }
  }
  float tb = l2b[k] + bias[k] + lmb[k] + ldb[k];
  float rb = l1b[k];
#pragma unroll
  for (int u = 0; u < 4; ++u) {
    int row = row0 + lr * 4 + u;
    rbuf[row * 64 + k] = a1[u] + rb;
    tbuf[row * 64 + k] = a2[u] + tb;
  }
}

// ---- GEMM1: tmp[m][n'] = ctx_h[m][:] . wt[n'][:]  (M=2048, N=16384, K=256) ----
// BK=64, XOR-swizzled LDS (chunk ^= row&7), swapped MFMA (acc[ni][mi]),
// LDS-transpose epilogue -> half8 coalesced tmp stores.  (R2-proven loop.)
__global__ __launch_bounds__(256) void gemm1(const _Float16* __restrict__ ch,
                                             const _Float16* __restrict__ wt,
                                             _Float16* __restrict__ tmp) {
  // 36 KB pool: [0,16KB) As, [16KB,32KB) Bs during K-loop (128 rows x 64 halfs
  // each); 4x (64x72) fp16 per-wave transpose tiles in the epilogue.
  __shared__ _Float16 pool[4 * 64 * 72];
  _Float16* As = pool;           // 128*64 halfs
  _Float16* Bs = pool + 8192;    // 128*64 halfs
  const int t = threadIdx.x;
  const int lane = t & 63, wave = t >> 6;
  // XCD-chunked bijective swizzle: each XCD gets 16 consecutive n-panels x
  // all 16 m-panels (wt slice 1MB + ctx 1MB -> L2-resident).
  const int d = blockIdx.x + blockIdx.y * 128;
  const int w = (d & 7) * 256 + (d >> 3);
  const int m0 = (w & 15) * 128, n0 = (w >> 4) * 128;
  const int wm = (wave & 1) * 64, wn = (wave >> 1) * 64;
  const int r = lane & 15, q = lane >> 4;
  const int sr = r & 7;
  f32x4 acc[4][4] = {};  // acc[ni][mi]
  // Staging: thread t owns LDS (row = p*32 + (t>>3), chunk = t&7); global
  // source chunk is (t&7) ^ (row&7) so LDS[row][c] holds global chunk c^(row&7).
  const int cg = (t & 7) ^ ((t >> 3) & 7);
  const _Float16* gA = ch + (size_t)(m0 + (t >> 3)) * 256 + cg * 8;
  const _Float16* gB = wt + (size_t)(n0 + (t >> 3)) * 256 + cg * 8;
  for (int k0 = 0; k0 < 256; k0 += 64) {
#pragma unroll
    for (int p = 0; p < 4; ++p) {
      async16(gA + p * 32 * 256 + k0, &As[p * 2048 + t * 8]);
      async16(gB + p * 32 * 256 + k0, &Bs[p * 2048 + t * 8]);
    }
    __syncthreads();
#pragma unroll
    for (int kk = 0; kk < 2; ++kk) {
      const int ca = ((kk * 4 + q) ^ sr) * 8;  // swizzled 16B chunk offset
      half8 a[4], b[4];
#pragma unroll
      for (int mi = 0; mi < 4; ++mi)
        a[mi] = *(const half8*)&As[(wm + mi * 16 + r) * 64 + ca];
#pragma unroll
      for (int ni = 0; ni < 4; ++ni)
        b[ni] = *(const half8*)&Bs[(wn + ni * 16 + r) * 64 + ca];
#pragma unroll
      for (int ni = 0; ni < 4; ++ni)
#pragma unroll
        for (int mi = 0; mi < 4; ++mi)
          acc[ni][mi] = __builtin_amdgcn_mfma_f32_16x16x32_f16(
              b[ni], a[mi], acc[ni][mi], 0, 0, 0);
    }
    __syncthreads();
  }
  // Epilogue: per-wave 64x72 LDS tile [m][n], then 128B-coalesced half8 stores.
  _Float16* Sw = pool + wave * 4608;
#pragma unroll
  for (int ni = 0; ni < 4; ++ni)
#pragma unroll
    for (int mi = 0; mi < 4; ++mi) {
      half4v h;
#pragma unroll
      for (int e = 0; e < 4; ++e) h[e] = (_Float16)acc[ni][mi][e];
      *(half4v*)&Sw[(mi * 16 + r) * 72 + ni * 16 + q * 4] = h;
    }
  __syncthreads();
  const int g2 = lane >> 3, c2 = lane & 7;
  _Float16* dst = tmp + (size_t)(m0 + wm) * 16384 + (n0 + wn);
#pragma unroll
  for (int u = 0; u < 8; ++u) {
    int row = u * 8 + g2;
    half8 vv = *(const half8*)&Sw[row * 72 + c2 * 8];
    *(half8*)(dst + (size_t)row * 16384 + c2 * 8) = vv;
  }
}

// ---- GEMM2 + epilogue: one wide GEMM per batch b ----
// out_b[z][(s,k)] = ctx_b[z][:] . tmp_b[(s*64+k)][:]  (M=256, N=16384, K=256)
// tmp_b rows are j-contiguous. 128x128 tile, BK=64, T2 swizzle, swapped MFMA
// (acc[ni][mi]: lane holds 4 consecutive k) -> float4 r/t loads + tanh +
// float4 out stores. xcd = b (ctx_b/rbuf/tbuf L2-resident). (R3-proven loop.)
__global__ __launch_bounds__(256) void gemm2(const _Float16* __restrict__ ch,
                                             const _Float16* __restrict__ tmp,
                                             const float* __restrict__ rbuf,
                                             const float* __restrict__ tbuf,
                                             float* __restrict__ out) {
  __shared__ _Float16 As[128 * 64];  // ctx_b z-tile   16 KB
  __shared__ _Float16 Bs[128 * 64];  // tmp_b n-tile   16 KB
  const int t = threadIdx.x;
  const int lane = t & 63, wave = t >> 6;
  const int d = blockIdx.x;
  const int b = d & 7;               // xcd = b
  const int idx = d >> 3;            // [0,256)
  const int m0 = (idx & 1) * 128;    // z-tile
  const int n0 = (idx >> 1) * 128;   // (s,k)-tile
  const int wm = (wave & 1) * 64, wn = (wave >> 1) * 64;
  const int r = lane & 15, q = lane >> 4;
  const int sr = r & 7;
  f32x4 acc[4][4] = {};  // acc[ni][mi]
  const _Float16* chb = ch + (size_t)b * 65536;
  const _Float16* tmb = tmp + (size_t)b * 4194304;
  const int cg = (t & 7) ^ ((t >> 3) & 7);
  const _Float16* gA = chb + (size_t)(m0 + (t >> 3)) * 256 + cg * 8;
  const _Float16* gB = tmb + (size_t)(n0 + (t >> 3)) * 256 + cg * 8;
  for (int k0 = 0; k0 < 256; k0 += 64) {
#pragma unroll
    for (int p = 0; p < 4; ++p) {
      async16(gA + p * 32 * 256 + k0, &As[p * 2048 + t * 8]);
      async16(gB + p * 32 * 256 + k0, &Bs[p * 2048 + t * 8]);
    }
    __syncthreads();
#pragma unroll
    for (int kk = 0; kk < 2; ++kk) {
      const int ca = ((kk * 4 + q) ^ sr) * 8;
      half8 a[4], bf[4];
#pragma unroll
      for (int mi = 0; mi < 4; ++mi)
        a[mi] = *(const half8*)&As[(wm + mi * 16 + r) * 64 + ca];
#pragma unroll
      for (int ni = 0; ni < 4; ++ni)
        bf[ni] = *(const half8*)&Bs[(wn + ni * 16 + r) * 64 + ca];
#pragma unroll
      for (int ni = 0; ni < 4; ++ni)
#pragma unroll
        for (int mi = 0; mi < 4; ++mi)
          acc[ni][mi] = __builtin_amdgcn_mfma_f32_16x16x32_f16(
              bf[ni], a[mi], acc[ni][mi], 0, 0, 0);
    }
    __syncthreads();
  }
  // Epilogue: n = s_local*64 + k; per lane 4 consecutive k (never cross s).
  const int s = (n0 >> 6) + (wn >> 6);          // global s for this wave
  const float* rb = rbuf + (size_t)b * 16384;
  const float* tb = tbuf + ((size_t)(b * 256 + s)) * 64;
  float* ob = out + (size_t)b * 4194304 + (size_t)s * 16384;
#pragma unroll
  for (int ni = 0; ni < 4; ++ni)
#pragma unroll
    for (int mi = 0; mi < 4; ++mi) {
      int z = m0 + wm + mi * 16 + r;
      int k0 = ni * 16 + q * 4;
      f32x4 rv = *(const f32x4*)&rb[z * 64 + k0];
      f32x4 tv = *(const f32x4*)&tb[k0];
      f32x4 o;
#pragma unroll
      for (int e = 0; e < 4; ++e) {
        float x = acc[ni][mi][e] + rv[e] + tv[e];
        float ax = fabsf(x);
        float ev = __expf(-2.0f * ax);
        float y = (1.0f - ev) / (1.0f + ev);
        o[e] = copysignf(y, x);
      }
      *(f32x4*)&ob[z * 64 + k0] = o;
    }
}

extern "C" void kernel_launch(void* const* d_in, const int* in_sizes, int n_in,
                              void* d_out, int out_size, void* d_ws, size_t ws_size,
                              hipStream_t stream) {
  const float* ctx  = (const float*)d_in[0];
  const float* W    = (const float*)d_in[1];
  const float* bias = (const float*)d_in[2];
  const float* l1w  = (const float*)d_in[3];
  const float* l1b  = (const float*)d_in[4];
  const float* l2w  = (const float*)d_in[5];
  const float* l2b  = (const float*)d_in[6];
  const float* lmw  = (const float*)d_in[7];
  const float* lmb  = (const float*)d_in[8];
  const float* ldw  = (const float*)d_in[9];
  const float* ldb  = (const float*)d_in[10];
  float* out = (float*)d_out;

  char* ws = (char*)d_ws;
  _Float16* ch  = (_Float16*)ws;                               // 1 MiB ctx fp16
  _Float16* wt  = (_Float16*)(ws + (1u << 20));                // 8 MiB W_eff^T fp16
  _Float16* tmp = (_Float16*)(ws + (9u << 20));                // 64 MiB tmp fp16
  float* rbuf = (float*)(ws + (73u << 20));                    // 512 KiB
  float* tbuf = rbuf + 2048 * 64;                              // 512 KiB

  prep_all<<<384, 256, 0, stream>>>(ctx, W, bias, l1w, l1b, l2w, l2b, lmw, lmb,
                                    ldw, ldb, rbuf, tbuf, ch, wt);
  gemm1<<<dim3(128, 16), 256, 0, stream>>>(ch, wt, tmp);
  gemm2<<<2048, 256, 0, stream>>>(ch, tmp, rbuf, tbuf, out);
}